// Round 2
// baseline (422.869 us; speedup 1.0000x reference)
//
#include <hip/hip_runtime.h>
#include <hip/hip_bf16.h>

// Problem constants
#define B_   32
#define S_   512
#define NB_  20
#define EMB_ 128
#define VOC_ 40000

typedef float f32x4 __attribute__((ext_vector_type(4)));
typedef __bf16 bf16x8 __attribute__((ext_vector_type(8)));

union Frag {
  uint4 u;
  bf16x8 b;
  unsigned short s[8];
};

__device__ __forceinline__ unsigned short f2bf(float x){
  unsigned u = __float_as_uint(x);
  unsigned r = (u + 0x7FFFu + ((u>>16)&1u)) >> 16;  // round-to-nearest-even
  return (unsigned short)r;
}
__device__ __forceinline__ float bf2f(unsigned short s){
  return __uint_as_float(((unsigned)s)<<16);
}
__device__ __forceinline__ float tanh_fast(float x){
  float xx = fminf(fmaxf(x, -15.f), 15.f);
  float e = __expf(2.f*xx);
  return (e-1.f)/(e+1.f);
}

// ---------------------------------------------------------------------------
// Prep: u, qc = u@C, tf = u@F, uh = u@H, kb = emb[keys]@Bm (all fp32),
// plus hi/lo bf16 B-operand fragment layouts of A (K=128) and [D;E] (K=256).
// B-frag layout (16x16x32): chunk = ((ntile*KC + kc)*64 + lane), 8 bf16:
//   n = ntile*16 + (lane&15), k = kc*32 + (lane>>4)*8 + j
// ---------------------------------------------------------------------------
__global__ __launch_bounds__(128) void prep_kernel(
    const int* __restrict__ queries, const int* __restrict__ keys,
    const float* __restrict__ emb, const float* __restrict__ mmask,
    const float* __restrict__ A, const float* __restrict__ Bm,
    const float* __restrict__ C, const float* __restrict__ D,
    const float* __restrict__ E, const float* __restrict__ F,
    const float* __restrict__ H,
    float* __restrict__ qc_w, float* __restrict__ tf_w,
    float* __restrict__ uh_w, float* __restrict__ kb_w,
    unsigned short* __restrict__ afragH, unsigned short* __restrict__ afragL,
    unsigned short* __restrict__ w2fragH, unsigned short* __restrict__ w2fragL)
{
  int bid = blockIdx.x, tid = threadIdx.x;
  if (bid < 32) {
    __shared__ float ulds[128];
    int b = bid;
    float s = 0.f;
    for (int q=0;q<NB_;q++){
      int tok = queries[b*NB_+q];
      s += emb[tok*128+tid]*mmask[q*128+tid];
    }
    ulds[tid] = s;
    __syncthreads();
    float sq=0.f, sf=0.f, sh=0.f;
    for (int e=0;e<128;e++){
      float uv = ulds[e];
      sq += uv*C[e*128+tid];
      sf += uv*F[e*128+tid];
      sh += uv*H[e*128+tid];
    }
    qc_w[b*128+tid]=sq; tf_w[b*128+tid]=sf; uh_w[b*128+tid]=sh;
  } else if (bid < 52) {
    __shared__ float ek[128];
    int n = bid-32;
    int tok = keys[n];
    ek[tid] = emb[tok*128+tid];
    __syncthreads();
    float s=0.f;
    for (int e=0;e<128;e++) s += ek[e]*Bm[e*128+tid];
    kb_w[n*128+tid] = s;
  } else if (bid < 60) {
    // A fragments: ntiles=8, kc=4 -> 2048 chunks, hi+lo
    int a = bid-52;
    for (int cc=0;cc<2;cc++){
      int c = (a*128+tid)*2+cc;
      int lane = c&63, kc = (c>>6)&3, nt = c>>8;
      int n2 = nt*16 + (lane&15);
      int k0 = kc*32 + (lane>>4)*8;
      alignas(16) unsigned short th[8], tl[8];
      #pragma unroll
      for (int j=0;j<8;j++){
        float x = A[(k0+j)*128+n2];
        unsigned short h = f2bf(x);
        th[j] = h;
        tl[j] = f2bf(x - bf2f(h));
      }
      *(uint4*)(afragH + c*8) = *(const uint4*)th;
      *(uint4*)(afragL + c*8) = *(const uint4*)tl;
    }
  } else {
    // W2 = [D;E] fragments: ntiles=8, kc=8 -> 4096 chunks, hi+lo
    int wb = bid-60;
    for (int cc=0;cc<2;cc++){
      int c = (wb*128+tid)*2+cc;
      int lane = c&63, kc = (c>>6)&7, nt = c>>9;
      int n2 = nt*16 + (lane&15);
      int k0 = kc*32 + (lane>>4)*8;
      alignas(16) unsigned short th[8], tl[8];
      #pragma unroll
      for (int j=0;j<8;j++){
        int k = k0+j;
        float x = (k<128) ? D[k*128+n2] : E[(k-128)*128+n2];
        unsigned short h = f2bf(x);
        th[j] = h;
        tl[j] = f2bf(x - bf2f(h));
      }
      *(uint4*)(w2fragH + c*8) = *(const uint4*)th;
      *(uint4*)(w2fragL + c*8) = *(const uint4*)tl;
    }
  }
}

// ---------------------------------------------------------------------------
// K2a: per block, 4 (b,s) pairs -> M=80 rows (row = p*20+n), K=128, N=128.
// Split-bf16: ia = mh.Ah + ml.Ah + mh.Al  (fp32-accurate).
// Epilogue: intr_align = sum_i v_i tanh(ia + kb + qc), softmax over n,
// tm = attn.mem (hi+lo reconstruct).
// ---------------------------------------------------------------------------
__global__ __launch_bounds__(256) void k2a_kernel(
    const float* __restrict__ mem,
    const unsigned short* __restrict__ afragH, const unsigned short* __restrict__ afragL,
    const float* __restrict__ kb_w, const float* __restrict__ qc_w,
    const float* __restrict__ vvec, float* __restrict__ tm_w)
{
  __shared__ unsigned short mfrH[5*4*64*8];   // 20KB
  __shared__ unsigned short mfrL[5*4*64*8];   // 20KB
  __shared__ float alignP[4*80];
  __shared__ float aligns[80];
  __shared__ float attns[80];

  int g = blockIdx.x, tid = threadIdx.x;
  int b = g >> 7;   // 128 blocks (512 s / 4) per batch element

  // stage: 10240 contiguous floats -> hi/lo bf16 in A-frag scrambled LDS
  const float4* gm = (const float4*)(mem) + (size_t)g*2560;
  #pragma unroll
  for (int it=0; it<10; ++it){
    int i4 = tid + it*256;
    float4 d = gm[i4];
    int e4 = i4*4;
    int row = e4 >> 7;          // 0..79
    int k0 = e4 & 127;
    int mt = row >> 4;
    int lane = (((k0>>3)&3)<<4) | (row & 15);
    int chunk = (mt*4 + (k0>>5))*64 + lane;
    int sa = chunk*8 + (k0 & 7);
    unsigned short hx=f2bf(d.x), hy=f2bf(d.y), hz=f2bf(d.z), hw=f2bf(d.w);
    *(uint2*)(mfrH + sa) = make_uint2((unsigned)hx|((unsigned)hy<<16),
                                      (unsigned)hz|((unsigned)hw<<16));
    unsigned short lx=f2bf(d.x-bf2f(hx)), ly=f2bf(d.y-bf2f(hy));
    unsigned short lz=f2bf(d.z-bf2f(hz)), lw=f2bf(d.w-bf2f(hw));
    *(uint2*)(mfrL + sa) = make_uint2((unsigned)lx|((unsigned)ly<<16),
                                      (unsigned)lz|((unsigned)lw<<16));
  }
  __syncthreads();

  int w = tid>>6, lane = tid&63;
  int lo16_ = lane & 15, hi16_ = lane >> 4;
  int nt0 = 2*w, nt1 = 2*w+1;

  f32x4 acc[5][2];
  #pragma unroll
  for (int mt=0;mt<5;mt++){ acc[mt][0]=(f32x4)(0.f); acc[mt][1]=(f32x4)(0.f); }

  #pragma unroll
  for (int kc=0;kc<4;kc++){
    Frag b0h, b0l, b1h, b1l;
    b0h.u = *(const uint4*)(afragH + ((size_t)(nt0*4+kc)*64 + lane)*8);
    b0l.u = *(const uint4*)(afragL + ((size_t)(nt0*4+kc)*64 + lane)*8);
    b1h.u = *(const uint4*)(afragH + ((size_t)(nt1*4+kc)*64 + lane)*8);
    b1l.u = *(const uint4*)(afragL + ((size_t)(nt1*4+kc)*64 + lane)*8);
    #pragma unroll
    for (int mt=0;mt<5;mt++){
      Frag ah, al;
      ah.u = *(const uint4*)(mfrH + ((mt*4+kc)*64 + lane)*8);
      al.u = *(const uint4*)(mfrL + ((mt*4+kc)*64 + lane)*8);
      acc[mt][0] = __builtin_amdgcn_mfma_f32_16x16x32_bf16(ah.b, b0h.b, acc[mt][0], 0,0,0);
      acc[mt][0] = __builtin_amdgcn_mfma_f32_16x16x32_bf16(al.b, b0h.b, acc[mt][0], 0,0,0);
      acc[mt][0] = __builtin_amdgcn_mfma_f32_16x16x32_bf16(ah.b, b0l.b, acc[mt][0], 0,0,0);
      acc[mt][1] = __builtin_amdgcn_mfma_f32_16x16x32_bf16(ah.b, b1h.b, acc[mt][1], 0,0,0);
      acc[mt][1] = __builtin_amdgcn_mfma_f32_16x16x32_bf16(al.b, b1h.b, acc[mt][1], 0,0,0);
      acc[mt][1] = __builtin_amdgcn_mfma_f32_16x16x32_bf16(ah.b, b1l.b, acc[mt][1], 0,0,0);
    }
  }

  // epilogue: align[row] = sum_i v_i * tanh(ia[row,i] + kb[n,i] + qc[b,i])
  #pragma unroll
  for (int mt=0;mt<5;mt++){
    #pragma unroll
    for (int r=0;r<4;r++){
      unsigned row = mt*16 + hi16_*4 + r;
      unsigned p = row/20u;
      unsigned n = row - p*20u;
      float part = 0.f;
      #pragma unroll
      for (int t2=0;t2<2;t2++){
        int col = (2*w+t2)*16 + lo16_;
        float z = acc[mt][t2][r] + kb_w[n*128+col] + qc_w[b*128+col];
        part += vvec[col]*tanh_fast(z);
      }
      part += __shfl_xor(part, 1);
      part += __shfl_xor(part, 2);
      part += __shfl_xor(part, 4);
      part += __shfl_xor(part, 8);
      if (lo16_ == 0) alignP[w*80+row] = part;
    }
  }
  __syncthreads();
  if (tid < 80){
    aligns[tid] = alignP[tid] + alignP[80+tid] + alignP[160+tid] + alignP[240+tid];
  }
  __syncthreads();
  if (tid < 4){
    float mx = -1e30f;
    for (int n=0;n<NB_;n++) mx = fmaxf(mx, aligns[tid*NB_+n]);
    float s = 0.f;
    for (int n=0;n<NB_;n++){ float e = __expf(aligns[tid*NB_+n]-mx); attns[tid*NB_+n]=e; s+=e; }
    float inv = 1.f/s;
    for (int n=0;n<NB_;n++) attns[tid*NB_+n] *= inv;
  }
  __syncthreads();

  // tm[p][e] = sum_n attn * mem (hi+lo reconstruct from scrambled LDS)
  if (tid < 128){
    int p2 = tid>>5, e0 = (tid&31)*4;
    float4 o = make_float4(0.f,0.f,0.f,0.f);
    #pragma unroll
    for (int n=0;n<NB_;n++){
      int row = p2*NB_+n;
      float a = attns[row];
      int mt = row>>4;
      int lane2 = (((e0>>3)&3)<<4) | (row&15);
      int chunk = (mt*4 + (e0>>5))*64 + lane2;
      uint2 ph = *(const uint2*)(mfrH + chunk*8 + (e0&7));
      uint2 pl = *(const uint2*)(mfrL + chunk*8 + (e0&7));
      o.x += a*(bf2f((unsigned short)(ph.x&0xffffu)) + bf2f((unsigned short)(pl.x&0xffffu)));
      o.y += a*(bf2f((unsigned short)(ph.x>>16))    + bf2f((unsigned short)(pl.x>>16)));
      o.z += a*(bf2f((unsigned short)(ph.y&0xffffu)) + bf2f((unsigned short)(pl.y&0xffffu)));
      o.w += a*(bf2f((unsigned short)(ph.y>>16))    + bf2f((unsigned short)(pl.y>>16)));
    }
    *(float4*)(tm_w + ((size_t)g*4+p2)*128 + e0) = o;
  }
}

// ---------------------------------------------------------------------------
// K2b: per block 16 pairs, A-rows = [tm | stories] (K=256) split hi/lo,
// B = [D;E] split hi/lo.  talign = (mask!=0) ? mask*sum_i w_i tanh(td+te+tf) : -inf
// ---------------------------------------------------------------------------
__global__ __launch_bounds__(256) void k2b_kernel(
    const float* __restrict__ tm_w, const float* __restrict__ stories,
    const unsigned short* __restrict__ w2fragH, const unsigned short* __restrict__ w2fragL,
    const float* __restrict__ tf_w, const float* __restrict__ wvec,
    const float* __restrict__ smask, float* __restrict__ talign_w)
{
  __shared__ unsigned short afrH[8*64*8];  // 8KB
  __shared__ unsigned short afrL[8*64*8];  // 8KB
  __shared__ float partial[4*16];
  int gb = blockIdx.x, tid = threadIdx.x;
  int flat0 = gb*16;
  int b = flat0 >> 9;

  #pragma unroll
  for (int cc=0;cc<2;cc++){
    int c = tid*2+cc;                 // 0..511 chunks (kc=8 x lane=64)
    int lane = c&63, kc = c>>6;
    int p = lane&15;
    int k0 = kc*32 + (lane>>4)*8;
    const float* src = (k0 < 128)
        ? (tm_w + ((size_t)(flat0+p))*128 + k0)
        : (stories + ((size_t)(flat0+p))*128 + (k0-128));
    float4 s0 = *(const float4*)(src);
    float4 s1 = *(const float4*)(src+4);
    alignas(16) unsigned short th[8], tl[8];
    float xs[8] = {s0.x,s0.y,s0.z,s0.w,s1.x,s1.y,s1.z,s1.w};
    #pragma unroll
    for (int j=0;j<8;j++){
      unsigned short h = f2bf(xs[j]);
      th[j]=h; tl[j]=f2bf(xs[j]-bf2f(h));
    }
    *(uint4*)(afrH + c*8) = *(const uint4*)th;
    *(uint4*)(afrL + c*8) = *(const uint4*)tl;
  }
  __syncthreads();

  int w = tid>>6, lane = tid&63;
  int lo = lane&15, hi = lane>>4;
  f32x4 acc0 = (f32x4)(0.f), acc1 = (f32x4)(0.f);

  #pragma unroll
  for (int kc=0;kc<8;kc++){
    Frag ah, al, b0h, b0l, b1h, b1l;
    ah.u  = *(const uint4*)(afrH + (kc*64+lane)*8);
    al.u  = *(const uint4*)(afrL + (kc*64+lane)*8);
    b0h.u = *(const uint4*)(w2fragH + ((size_t)((2*w)*8+kc)*64+lane)*8);
    b0l.u = *(const uint4*)(w2fragL + ((size_t)((2*w)*8+kc)*64+lane)*8);
    b1h.u = *(const uint4*)(w2fragH + ((size_t)((2*w+1)*8+kc)*64+lane)*8);
    b1l.u = *(const uint4*)(w2fragL + ((size_t)((2*w+1)*8+kc)*64+lane)*8);
    acc0 = __builtin_amdgcn_mfma_f32_16x16x32_bf16(ah.b, b0h.b, acc0, 0,0,0);
    acc0 = __builtin_amdgcn_mfma_f32_16x16x32_bf16(al.b, b0h.b, acc0, 0,0,0);
    acc0 = __builtin_amdgcn_mfma_f32_16x16x32_bf16(ah.b, b0l.b, acc0, 0,0,0);
    acc1 = __builtin_amdgcn_mfma_f32_16x16x32_bf16(ah.b, b1h.b, acc1, 0,0,0);
    acc1 = __builtin_amdgcn_mfma_f32_16x16x32_bf16(al.b, b1h.b, acc1, 0,0,0);
    acc1 = __builtin_amdgcn_mfma_f32_16x16x32_bf16(ah.b, b1l.b, acc1, 0,0,0);
  }

  #pragma unroll
  for (int r=0;r<4;r++){
    int prow = hi*4+r;
    float part = 0.f;
    {
      int i0 = (2*w)*16+lo;
      part += wvec[i0]*tanh_fast(acc0[r] + tf_w[b*128+i0]);
      int i1 = (2*w+1)*16+lo;
      part += wvec[i1]*tanh_fast(acc1[r] + tf_w[b*128+i1]);
    }
    part += __shfl_xor(part,1);
    part += __shfl_xor(part,2);
    part += __shfl_xor(part,4);
    part += __shfl_xor(part,8);
    if (lo==0) partial[w*16+prow] = part;
  }
  __syncthreads();
  if (tid<16){
    float ta = partial[tid]+partial[16+tid]+partial[32+tid]+partial[48+tid];
    int flat = flat0+tid;
    float m = smask[flat];
    talign_w[flat] = (m != 0.0f) ? ta*m : -INFINITY;
  }
}

// ---------------------------------------------------------------------------
// K3a: softmax over S=512 per batch element
// ---------------------------------------------------------------------------
__global__ __launch_bounds__(256) void k3a_kernel(
    const float* __restrict__ talign_w, float* __restrict__ attn_w)
{
  __shared__ float red[256];
  int b = blockIdx.x, tid = threadIdx.x;
  float v0 = talign_w[b*512+tid];
  float v1 = talign_w[b*512+256+tid];
  red[tid] = fmaxf(v0,v1);
  __syncthreads();
  for (int s=128;s>0;s>>=1){ if (tid<s) red[tid]=fmaxf(red[tid],red[tid+s]); __syncthreads(); }
  float M = red[0];
  __syncthreads();
  float e0 = __expf(v0-M), e1 = __expf(v1-M);
  red[tid] = e0+e1;
  __syncthreads();
  for (int s=128;s>0;s>>=1){ if (tid<s) red[tid]+=red[tid+s]; __syncthreads(); }
  float invZ = 1.f/red[0];
  attn_w[b*512+tid] = e0*invZ;
  attn_w[b*512+256+tid] = e1*invZ;
}

// ---------------------------------------------------------------------------
// K3p: partial o = sum_s attn*tm over 64-s chunks
// ---------------------------------------------------------------------------
__global__ __launch_bounds__(256) void k3p_kernel(
    const float* __restrict__ attn_w, const float* __restrict__ tm_w,
    float* __restrict__ opart)
{
  __shared__ float part[256];
  int bc = blockIdx.x, tid = threadIdx.x;
  int b = bc>>3, c = bc&7;
  int e = tid&127, h = tid>>7;
  float a = 0.f;
  int sbase = c*64 + h;
  #pragma unroll 4
  for (int i=0;i<32;i++){
    int s = sbase + i*2;
    a += attn_w[b*512+s]*tm_w[((size_t)(b*512+s))*128 + e];
  }
  part[tid] = a;
  __syncthreads();
  if (tid<128) opart[bc*128+tid] = part[tid]+part[tid+128];
}

// ---------------------------------------------------------------------------
// K3b: ov = sum_c opart + uh
// ---------------------------------------------------------------------------
__global__ __launch_bounds__(256) void k3b_kernel(
    const float* __restrict__ opart, const float* __restrict__ uh_w,
    float* __restrict__ ov_w)
{
  int idx = blockIdx.x*256 + threadIdx.x;  // 0..4095
  int b = idx>>7, e = idx&127;
  float s = uh_w[idx];
  #pragma unroll
  for (int c=0;c<8;c++) s += opart[(b*8+c)*128 + e];
  ov_w[idx] = s;
}

// ---------------------------------------------------------------------------
// K4: logits[b][j] = sum_e ov[b][e]*R[e][j]
// ---------------------------------------------------------------------------
__global__ __launch_bounds__(256) void k4_kernel(
    const float* __restrict__ ov_w, const float* __restrict__ R,
    float* __restrict__ out)
{
  int j = blockIdx.x*256 + threadIdx.x;
  if (j >= VOC_) return;
  float acc[32];
  #pragma unroll
  for (int b=0;b<32;b++) acc[b]=0.f;
  for (int e=0;e<128;e++){
    float r = R[(size_t)e*VOC_ + j];
    #pragma unroll
    for (int b=0;b<32;b++) acc[b] += ov_w[b*128+e]*r;
  }
  #pragma unroll
  for (int b=0;b<32;b++) out[(size_t)b*VOC_ + j] = acc[b];
}

// ---------------------------------------------------------------------------
extern "C" void kernel_launch(void* const* d_in, const int* in_sizes, int n_in,
                              void* d_out, int out_size, void* d_ws, size_t ws_size,
                              hipStream_t stream)
{
  const float* mem    = (const float*)d_in[0];
  const float* stories= (const float*)d_in[1];
  const float* smask  = (const float*)d_in[2];
  const int*   queries= (const int*)d_in[3];
  const int*   keys   = (const int*)d_in[4];
  const float* emb    = (const float*)d_in[5];
  const float* mmask  = (const float*)d_in[6];
  const float* A      = (const float*)d_in[7];
  const float* Bm     = (const float*)d_in[8];
  const float* C      = (const float*)d_in[9];
  const float* vvec   = (const float*)d_in[10];
  const float* D      = (const float*)d_in[11];
  const float* E      = (const float*)d_in[12];
  const float* F      = (const float*)d_in[13];
  const float* wvec   = (const float*)d_in[14];
  const float* H      = (const float*)d_in[15];
  const float* R      = (const float*)d_in[16];
  float* out = (float*)d_out;

  char* ws = (char*)d_ws;
  float* qc_w             = (float*)(ws + 0);        // 16384
  float* tf_w             = (float*)(ws + 16384);    // 16384
  float* uh_w             = (float*)(ws + 32768);    // 16384
  float* kb_w             = (float*)(ws + 49152);    // 10240
  unsigned short* afragH  = (unsigned short*)(ws + 60416);   // 32768
  unsigned short* afragL  = (unsigned short*)(ws + 93184);   // 32768
  unsigned short* w2fragH = (unsigned short*)(ws + 125952);  // 65536
  unsigned short* w2fragL = (unsigned short*)(ws + 191488);  // 65536
  float* tm_w             = (float*)(ws + 257024);   // 8388608
  float* talign_w         = (float*)(ws + 8645632);  // 65536
  float* attn_w           = (float*)(ws + 8711168);  // 65536
  float* opart            = (float*)(ws + 8776704);  // 131072
  float* ov_w             = (float*)(ws + 8907776);  // 16384

  prep_kernel<<<76,128,0,stream>>>(queries, keys, emb, mmask, A, Bm, C, D, E, F, H,
                                   qc_w, tf_w, uh_w, kb_w,
                                   afragH, afragL, w2fragH, w2fragL);
  k2a_kernel<<<4096,256,0,stream>>>(mem, afragH, afragL, kb_w, qc_w, vvec, tm_w);
  k2b_kernel<<<1024,256,0,stream>>>(tm_w, stories, w2fragH, w2fragL, tf_w, wvec, smask, talign_w);
  k3a_kernel<<<32,256,0,stream>>>(talign_w, attn_w);
  k3p_kernel<<<256,256,0,stream>>>(attn_w, tm_w, opart);
  k3b_kernel<<<16,256,0,stream>>>(opart, uh_w, ov_w);
  k4_kernel<<<157,256,0,stream>>>(ov_w, R, out);
}

// Round 4
// 376.244 us; speedup vs baseline: 1.1239x; 1.1239x over previous
//
#include <hip/hip_runtime.h>
#include <hip/hip_bf16.h>

// Problem constants
#define B_   32
#define S_   512
#define NB_  20
#define EMB_ 128
#define VOC_ 40000

typedef float f32x4 __attribute__((ext_vector_type(4)));
typedef _Float16 f16x8 __attribute__((ext_vector_type(8)));
typedef __fp16 fp16x2 __attribute__((ext_vector_type(2)));

union FragH { uint4 u; f16x8 h; };
union H2 { fp16x2 h; unsigned u; };

__device__ __forceinline__ unsigned pk2(float a, float b){
  H2 t; t.h = __builtin_amdgcn_cvt_pkrtz(a, b);
  return t.u;
}
__device__ __forceinline__ unsigned short f2h(float x){
  _Float16 h = (_Float16)x;   // RNE
  return __builtin_bit_cast(unsigned short, h);
}
__device__ __forceinline__ float tanh_fast(float x){
  float xx = fminf(fmaxf(x, -15.f), 15.f);
  float e = __expf(2.f*xx);
  return (e-1.f)/(e+1.f);
}

// LDS fragment-slot swizzle: element (row,k) -> chunk/halfword
//   mt=row>>4, r=row&15, kg=k>>5, s2=(k>>3)&3, off=k&7
//   slot = s2<<4 | ((r ^ s2 ^ ((kg&1)<<2)) & 15)
//   chunk = (mt*4+kg)*64 + slot ; halfword = chunk*8 + off
// Reader lane l for (mt,kc): s2=l>>4, r=l&15  -> one ds_read_b128.

// ---------------------------------------------------------------------------
// Prep: u, qc=u@C, tf=u@F, uh=u@H, kb=emb[keys]@Bm (fp32),
// plus fp16 B-operand fragments of A (K=128) and [D;E] (K=256).
// B-frag: chunk=((nt*KC+kc)*64+lane): n=nt*16+(lane&15), k=kc*32+(lane>>4)*8+j
// ---------------------------------------------------------------------------
__global__ __launch_bounds__(128) void prep_kernel(
    const int* __restrict__ queries, const int* __restrict__ keys,
    const float* __restrict__ emb, const float* __restrict__ mmask,
    const float* __restrict__ A, const float* __restrict__ Bm,
    const float* __restrict__ C, const float* __restrict__ D,
    const float* __restrict__ E, const float* __restrict__ F,
    const float* __restrict__ H,
    float* __restrict__ qc_w, float* __restrict__ tf_w,
    float* __restrict__ uh_w, float* __restrict__ kb_w,
    unsigned short* __restrict__ afrag, unsigned short* __restrict__ w2frag)
{
  int bid = blockIdx.x, tid = threadIdx.x;
  if (bid < 32) {
    __shared__ float ulds[128];
    int b = bid;
    float s = 0.f;
    for (int q=0;q<NB_;q++){
      int tok = queries[b*NB_+q];
      s += emb[tok*128+tid]*mmask[q*128+tid];
    }
    ulds[tid] = s;
    __syncthreads();
    float sq=0.f, sf=0.f, sh=0.f;
    for (int e=0;e<128;e++){
      float uv = ulds[e];
      sq += uv*C[e*128+tid];
      sf += uv*F[e*128+tid];
      sh += uv*H[e*128+tid];
    }
    qc_w[b*128+tid]=sq; tf_w[b*128+tid]=sf; uh_w[b*128+tid]=sh;
  } else if (bid < 52) {
    __shared__ float ek[128];
    int n = bid-32;
    int tok = keys[n];
    ek[tid] = emb[tok*128+tid];
    __syncthreads();
    float s=0.f;
    for (int e=0;e<128;e++) s += ek[e]*Bm[e*128+tid];
    kb_w[n*128+tid] = s;
  } else if (bid < 60) {
    // A fragments: nt=8, kc=4 -> 2048 chunks fp16
    int a = bid-52;
    for (int cc=0;cc<2;cc++){
      int c = (a*128+tid)*2+cc;
      int lane = c&63, kc = (c>>6)&3, nt = c>>8;
      int n2 = nt*16 + (lane&15);
      int k0 = kc*32 + (lane>>4)*8;
      alignas(16) unsigned short t[8];
      #pragma unroll
      for (int j=0;j<8;j++) t[j] = f2h(A[(k0+j)*128+n2]);
      *(uint4*)(afrag + c*8) = *(const uint4*)t;
    }
  } else {
    // W2=[D;E] fragments: nt=8, kc=8 -> 4096 chunks fp16
    int wb = bid-60;
    for (int cc=0;cc<2;cc++){
      int c = (wb*128+tid)*2+cc;
      int lane = c&63, kc = (c>>6)&7, nt = c>>9;
      int n2 = nt*16 + (lane&15);
      int k0 = kc*32 + (lane>>4)*8;
      alignas(16) unsigned short t[8];
      #pragma unroll
      for (int j=0;j<8;j++){
        int k = k0+j;
        float x = (k<128) ? D[k*128+n2] : E[(k-128)*128+n2];
        t[j] = f2h(x);
      }
      *(uint4*)(w2frag + c*8) = *(const uint4*)t;
    }
  }
}

// ---------------------------------------------------------------------------
// K2a: 4 (b,s) pairs/block -> M=80 rows (row=p*20+n), K=128, N=128, fp16 MFMA.
// Swizzled LDS staging (conflict-free writes & reads). Epilogue:
// align = sum_i v_i tanh(ia+kb+qc); softmax over n; tm = attn.mem.
// ---------------------------------------------------------------------------
__global__ __launch_bounds__(256) void k2a_kernel(
    const float* __restrict__ mem, const unsigned short* __restrict__ afrag,
    const float* __restrict__ kb_w, const float* __restrict__ qc_w,
    const float* __restrict__ vvec, float* __restrict__ tm_w)
{
  __shared__ unsigned short mfr[5*4*64*8];   // 20KB fp16 tile
  __shared__ float alignP[4*80];
  __shared__ float aligns[80];
  __shared__ float attns[80];

  int g = blockIdx.x, tid = threadIdx.x;
  int b = g >> 7;   // 128 blocks per batch element

  // stage: 10240 contiguous floats -> fp16, swizzled frag layout
  const float4* gm = (const float4*)(mem) + (size_t)g*2560;
  #pragma unroll
  for (int it=0; it<10; ++it){
    int i4 = tid + it*256;
    float4 d = gm[i4];
    int e4 = i4*4;
    int row = e4 >> 7;          // 0..79
    int k = e4 & 127;
    int mt = row>>4, r = row&15;
    int kg = k>>5, s2 = (k>>3)&3;
    int slot = (s2<<4) | ((r ^ s2 ^ ((kg&1)<<2)) & 15);
    int chunk = (mt*4+kg)*64 + slot;
    *(uint2*)(mfr + chunk*8 + (k&7)) = make_uint2(pk2(d.x,d.y), pk2(d.z,d.w));
  }
  __syncthreads();

  int w = tid>>6, lane = tid&63;
  int lo16 = lane & 15, hi16 = lane >> 4;

  f32x4 acc[5][2];
  #pragma unroll
  for (int mt=0;mt<5;mt++){ acc[mt][0]=(f32x4)(0.f); acc[mt][1]=(f32x4)(0.f); }

  #pragma unroll
  for (int kc=0;kc<4;kc++){
    FragH b0, b1;
    b0.u = *(const uint4*)(afrag + ((size_t)((2*w)*4+kc)*64 + lane)*8);
    b1.u = *(const uint4*)(afrag + ((size_t)((2*w+1)*4+kc)*64 + lane)*8);
    int slot = (hi16<<4) | ((lo16 ^ hi16 ^ ((kc&1)<<2)) & 15);
    #pragma unroll
    for (int mt=0;mt<5;mt++){
      FragH a;
      a.u = *(const uint4*)(mfr + ((mt*4+kc)*64 + slot)*8);
      acc[mt][0] = __builtin_amdgcn_mfma_f32_16x16x32_f16(a.h, b0.h, acc[mt][0], 0,0,0);
      acc[mt][1] = __builtin_amdgcn_mfma_f32_16x16x32_f16(a.h, b1.h, acc[mt][1], 0,0,0);
    }
  }

  // epilogue: align[row] = sum_i v_i * tanh(ia + kb[n,i] + qc[b,i])
  #pragma unroll
  for (int mt=0;mt<5;mt++){
    #pragma unroll
    for (int r=0;r<4;r++){
      unsigned row = mt*16 + hi16*4 + r;
      unsigned p = row/20u;
      unsigned n = row - p*20u;
      float part = 0.f;
      #pragma unroll
      for (int t2=0;t2<2;t2++){
        int col = (2*w+t2)*16 + lo16;
        float z = acc[mt][t2][r] + kb_w[n*128+col] + qc_w[b*128+col];
        part += vvec[col]*tanh_fast(z);
      }
      part += __shfl_xor(part, 1);
      part += __shfl_xor(part, 2);
      part += __shfl_xor(part, 4);
      part += __shfl_xor(part, 8);
      if (lo16 == 0) alignP[w*80+row] = part;
    }
  }
  __syncthreads();
  if (tid < 80){
    aligns[tid] = alignP[tid] + alignP[80+tid] + alignP[160+tid] + alignP[240+tid];
  }
  __syncthreads();
  if (tid < 4){
    float mx = -1e30f;
    for (int n=0;n<NB_;n++) mx = fmaxf(mx, aligns[tid*NB_+n]);
    float s = 0.f;
    for (int n=0;n<NB_;n++){ float e = __expf(aligns[tid*NB_+n]-mx); attns[tid*NB_+n]=e; s+=e; }
    float inv = 1.f/s;
    for (int n=0;n<NB_;n++) attns[tid*NB_+n] *= inv;
  }
  __syncthreads();

  // tm[p][e] = sum_n attn * mem (fp16 from swizzled LDS)
  if (tid < 128){
    int p2 = tid>>5, e0 = (tid&31)*4;
    int kg = e0>>5, s2 = (e0>>3)&3;
    float4 o = make_float4(0.f,0.f,0.f,0.f);
    #pragma unroll
    for (int n=0;n<NB_;n++){
      int row = p2*NB_+n;
      float a = attns[row];
      int mt = row>>4, r = row&15;
      int slot = (s2<<4) | ((r ^ s2 ^ ((kg&1)<<2)) & 15);
      int chunk = (mt*4+kg)*64 + slot;
      uint2 pk = *(const uint2*)(mfr + chunk*8 + (e0&7));
      H2 q0, q1; q0.u = pk.x; q1.u = pk.y;
      o.x += a*(float)q0.h[0];
      o.y += a*(float)q0.h[1];
      o.z += a*(float)q1.h[0];
      o.w += a*(float)q1.h[1];
    }
    *(float4*)(tm_w + ((size_t)g*4+p2)*128 + e0) = o;
  }
}

// ---------------------------------------------------------------------------
// K2b: 16 pairs/block, A=[tm|stories] (K=256) fp16, B=[D;E] fp16.
// talign = (mask!=0) ? mask*sum_i w_i tanh(td+te+tf) : -inf
// ---------------------------------------------------------------------------
__global__ __launch_bounds__(256) void k2b_kernel(
    const float* __restrict__ tm_w, const float* __restrict__ stories,
    const unsigned short* __restrict__ w2frag, const float* __restrict__ tf_w,
    const float* __restrict__ wvec, const float* __restrict__ smask,
    float* __restrict__ talign_w)
{
  __shared__ unsigned short afr[512*8];  // 8KB
  __shared__ float partial[4*16];
  int gb = blockIdx.x, tid = threadIdx.x;
  int flat0 = gb*16;
  int b = flat0 >> 9;

  // stage: one 16B chunk per thread per iter -> conflict-free linear writes
  #pragma unroll
  for (int it=0;it<2;it++){
    int c = tid + it*256;             // chunk = kc*64 + lane
    int lane = c&63, kc = c>>6;
    int p = lane&15;
    int k0 = kc*32 + (lane>>4)*8;
    const float* src = (k0 < 128)
        ? (tm_w + ((size_t)(flat0+p))*128 + k0)
        : (stories + ((size_t)(flat0+p))*128 + (k0-128));
    float4 s0 = *(const float4*)(src);
    float4 s1 = *(const float4*)(src+4);
    uint4 pkd;
    pkd.x = pk2(s0.x,s0.y); pkd.y = pk2(s0.z,s0.w);
    pkd.z = pk2(s1.x,s1.y); pkd.w = pk2(s1.z,s1.w);
    *(uint4*)(afr + c*8) = pkd;
  }
  __syncthreads();

  int w = tid>>6, lane = tid&63;
  int lo = lane&15, hi = lane>>4;
  f32x4 acc0 = (f32x4)(0.f), acc1 = (f32x4)(0.f);

  #pragma unroll
  for (int kc=0;kc<8;kc++){
    FragH af, b0, b1;
    af.u = *(const uint4*)(afr + (kc*64+lane)*8);
    b0.u = *(const uint4*)(w2frag + ((size_t)((2*w)*8+kc)*64+lane)*8);
    b1.u = *(const uint4*)(w2frag + ((size_t)((2*w+1)*8+kc)*64+lane)*8);
    acc0 = __builtin_amdgcn_mfma_f32_16x16x32_f16(af.h, b0.h, acc0, 0,0,0);
    acc1 = __builtin_amdgcn_mfma_f32_16x16x32_f16(af.h, b1.h, acc1, 0,0,0);
  }

  #pragma unroll
  for (int r=0;r<4;r++){
    int prow = hi*4+r;
    float part = 0.f;
    {
      int i0 = (2*w)*16+lo;
      part += wvec[i0]*tanh_fast(acc0[r] + tf_w[b*128+i0]);
      int i1 = (2*w+1)*16+lo;
      part += wvec[i1]*tanh_fast(acc1[r] + tf_w[b*128+i1]);
    }
    part += __shfl_xor(part,1);
    part += __shfl_xor(part,2);
    part += __shfl_xor(part,4);
    part += __shfl_xor(part,8);
    if (lo==0) partial[w*16+prow] = part;
  }
  __syncthreads();
  if (tid<16){
    float ta = partial[tid]+partial[16+tid]+partial[32+tid]+partial[48+tid];
    int flat = flat0+tid;
    float m = smask[flat];
    talign_w[flat] = (m != 0.0f) ? ta*m : -INFINITY;
  }
}

// ---------------------------------------------------------------------------
// K3 (merged): softmax over S=512, o = sum_s attn*tm, ov = o + uh
// ---------------------------------------------------------------------------
__global__ __launch_bounds__(256) void k3_kernel(
    const float* __restrict__ talign_w, const float* __restrict__ tm_w,
    const float* __restrict__ uh_w, float* __restrict__ ov_w)
{
  __shared__ float attn[512];
  __shared__ float red[256];
  int b = blockIdx.x, tid = threadIdx.x;
  float v0 = talign_w[b*512+tid];
  float v1 = talign_w[b*512+256+tid];
  red[tid] = fmaxf(v0,v1);
  __syncthreads();
  for (int s=128;s>0;s>>=1){ if (tid<s) red[tid]=fmaxf(red[tid],red[tid+s]); __syncthreads(); }
  float M = red[0];
  __syncthreads();
  float e0 = __expf(v0-M), e1 = __expf(v1-M);
  red[tid] = e0+e1;
  __syncthreads();
  for (int s=128;s>0;s>>=1){ if (tid<s) red[tid]+=red[tid+s]; __syncthreads(); }
  float invZ = 1.f/red[0];
  attn[tid] = e0*invZ;
  attn[256+tid] = e1*invZ;
  __syncthreads();

  int e = tid&127, h = tid>>7;
  const float* tmb = tm_w + ((size_t)b*512 + h*256)*128 + e;
  float a = 0.f;
  #pragma unroll 4
  for (int i=0;i<256;i++){
    a += attn[h*256+i]*tmb[(size_t)i*128];
  }
  red[tid] = a;
  __syncthreads();
  if (tid<128) ov_w[b*128+tid] = red[tid]+red[128+tid]+uh_w[b*128+tid];
}

// ---------------------------------------------------------------------------
// K4: logits[b][j] = sum_e ov[b][e]*R[e][j]; 625 blocks, j-tile 64, 4 b-groups
// ---------------------------------------------------------------------------
__global__ __launch_bounds__(256) void k4_kernel(
    const float* __restrict__ ov_w, const float* __restrict__ R,
    float* __restrict__ out)
{
  int tid = threadIdx.x;
  int j = blockIdx.x*64 + (tid&63);
  int bh = tid>>6;                 // 0..3 -> b = bh*8 + bb
  const float* ovb = ov_w + bh*8*128;
  float acc[8];
  #pragma unroll
  for (int bb=0;bb<8;bb++) acc[bb]=0.f;
  for (int e=0;e<128;e+=4){
    float r0 = R[(size_t)(e+0)*VOC_ + j];
    float r1 = R[(size_t)(e+1)*VOC_ + j];
    float r2 = R[(size_t)(e+2)*VOC_ + j];
    float r3 = R[(size_t)(e+3)*VOC_ + j];
    #pragma unroll
    for (int bb=0;bb<8;bb++){
      acc[bb] += ovb[bb*128+e+0]*r0 + ovb[bb*128+e+1]*r1
               + ovb[bb*128+e+2]*r2 + ovb[bb*128+e+3]*r3;
    }
  }
  #pragma unroll
  for (int bb=0;bb<8;bb++) out[(size_t)(bh*8+bb)*VOC_ + j] = acc[bb];
}

// ---------------------------------------------------------------------------
extern "C" void kernel_launch(void* const* d_in, const int* in_sizes, int n_in,
                              void* d_out, int out_size, void* d_ws, size_t ws_size,
                              hipStream_t stream)
{
  const float* mem    = (const float*)d_in[0];
  const float* stories= (const float*)d_in[1];
  const float* smask  = (const float*)d_in[2];
  const int*   queries= (const int*)d_in[3];
  const int*   keys   = (const int*)d_in[4];
  const float* emb    = (const float*)d_in[5];
  const float* mmask  = (const float*)d_in[6];
  const float* A      = (const float*)d_in[7];
  const float* Bm     = (const float*)d_in[8];
  const float* C      = (const float*)d_in[9];
  const float* vvec   = (const float*)d_in[10];
  const float* D      = (const float*)d_in[11];
  const float* E      = (const float*)d_in[12];
  const float* F      = (const float*)d_in[13];
  const float* wvec   = (const float*)d_in[14];
  const float* H      = (const float*)d_in[15];
  const float* R      = (const float*)d_in[16];
  float* out = (float*)d_out;

  char* ws = (char*)d_ws;
  float* qc_w             = (float*)(ws + 0);         // 16384
  float* tf_w             = (float*)(ws + 16384);     // 16384
  float* uh_w             = (float*)(ws + 32768);     // 16384
  float* kb_w             = (float*)(ws + 49152);     // 10240
  unsigned short* afrag   = (unsigned short*)(ws + 60416);   // 32768
  unsigned short* w2frag  = (unsigned short*)(ws + 93184);   // 65536
  float* tm_w             = (float*)(ws + 158720);    // 8388608
  float* talign_w         = (float*)(ws + 8547328);   // 65536
  float* ov_w             = (float*)(ws + 8612864);   // 16384

  prep_kernel<<<76,128,0,stream>>>(queries, keys, emb, mmask, A, Bm, C, D, E, F, H,
                                   qc_w, tf_w, uh_w, kb_w, afrag, w2frag);
  k2a_kernel<<<4096,256,0,stream>>>(mem, afrag, kb_w, qc_w, vvec, tm_w);
  k2b_kernel<<<1024,256,0,stream>>>(tm_w, stories, w2frag, tf_w, wvec, smask, talign_w);
  k3_kernel<<<32,256,0,stream>>>(talign_w, tm_w, uh_w, ov_w);
  k4_kernel<<<625,256,0,stream>>>(ov_w, R, out);
}